// Round 6
// baseline (443.493 us; speedup 1.0000x reference)
//
#include <hip/hip_runtime.h>

typedef unsigned long long u64;

#define K_TOP 5000
#define NMS_THR_F 0.4f
#define CONF_THR_F 0.6f
#define W_WORDS 80          // ceil(5000/64)=79, padded to 80
#define ROWS_PAD 5056       // mat rows allocated (>= 5008 tile reach)
#define CHUNK 8192          // elements per block in select pass
#define TPB 256

// ---------------- pass 1: per-block count of score>thr ----------------
__global__ __launch_bounds__(TPB)
void count_kernel(const float* __restrict__ conf, int N, int* __restrict__ counts) {
  int tid = threadIdx.x;
  long long base = (long long)blockIdx.x * CHUNK + (long long)tid * 32;
  int cnt = 0;
  if (base + 32 <= N) {
    const float4* c4 = (const float4*)conf;
    long long f0 = base >> 1;            // float4 index (2 anchors per float4)
    #pragma unroll
    for (int k = 0; k < 16; ++k) {
      float4 v = c4[f0 + k];
      cnt += (v.y > CONF_THR_F);
      cnt += (v.w > CONF_THR_F);
    }
  } else {
    for (int k = 0; k < 32; ++k) {
      long long n = base + k;
      if (n < N) cnt += (conf[2*n+1] > CONF_THR_F);
    }
  }
  __shared__ int s[TPB];
  s[tid] = cnt; __syncthreads();
  for (int d = TPB/2; d > 0; d >>= 1) {
    if (tid < d) s[tid] += s[tid+d];
    __syncthreads();
  }
  if (tid == 0) counts[blockIdx.x] = s[0];
}

// ---------------- pass 2: exclusive scan of block counts ----------------
__global__ __launch_bounds__(TPB)
void scan_kernel(const int* __restrict__ counts, int* __restrict__ offsets,
                 int* __restrict__ meta, int NB) {
  __shared__ int s[TPB];
  __shared__ int carry;
  int tid = threadIdx.x;
  if (tid == 0) carry = 0;
  __syncthreads();
  for (int base = 0; base < NB; base += TPB) {
    int idx = base + tid;
    int c = (idx < NB) ? counts[idx] : 0;
    s[tid] = c; __syncthreads();
    for (int d = 1; d < TPB; d <<= 1) {
      int v = (tid >= d) ? s[tid - d] : 0;
      __syncthreads();
      s[tid] += v;
      __syncthreads();
    }
    int excl = s[tid] - c + carry;
    if (idx < NB) offsets[idx] = excl;
    __syncthreads();                       // all threads done reading carry
    if (tid == 0) carry += s[TPB-1];
    __syncthreads();
  }
  if (tid == 0) {
    int total = carry;
    meta[0] = total < K_TOP ? total : K_TOP;  // M = number of valid slots
    meta[1] = total;
  }
}

// ---------------- pass 3: stable compaction of first K indices ----------------
__global__ __launch_bounds__(TPB)
void emit_kernel(const float* __restrict__ conf, int N,
                 const int* __restrict__ offsets, int* __restrict__ sel) {
  int tid = threadIdx.x;
  int boff = offsets[blockIdx.x];          // uniform
  if (boff >= K_TOP) return;               // uniform exit, before any barrier
  long long base = (long long)blockIdx.x * CHUNK + (long long)tid * 32;
  unsigned mbits = 0;
  if (base + 32 <= N) {
    const float4* c4 = (const float4*)conf;
    long long f0 = base >> 1;
    #pragma unroll
    for (int k = 0; k < 16; ++k) {
      float4 v = c4[f0 + k];
      mbits |= (unsigned)(v.y > CONF_THR_F) << (2*k);
      mbits |= (unsigned)(v.w > CONF_THR_F) << (2*k+1);
    }
  } else {
    for (int k = 0; k < 32; ++k) {
      long long n = base + k;
      if (n < N && conf[2*n+1] > CONF_THR_F) mbits |= 1u << k;
    }
  }
  int cnt = __popc(mbits);
  __shared__ int s[TPB];
  s[tid] = cnt; __syncthreads();
  for (int d = 1; d < TPB; d <<= 1) {
    int v = (tid >= d) ? s[tid - d] : 0;
    __syncthreads();
    s[tid] += v;
    __syncthreads();
  }
  int rank = boff + s[tid] - cnt;          // exclusive prefix within block + block offset
  if (mbits && rank < K_TOP) {
    for (int k = 0; k < 32; ++k) {
      if ((mbits >> k) & 1u) {
        if (rank < K_TOP) sel[rank] = (int)(base + k);
        ++rank;
      }
    }
  }
}

// scalar inputs arrive as 1-element arrays; dtype could be int32 or float32.
// Decode both ways and pick the interpretation in a sane range (exact for 1664
// either way; 1664.0f's bit pattern reads as 1.15e9 which is rejected).
__device__ __forceinline__ float scalar_to_float(const int* p) {
  int iv = *p;
  float fv = __int_as_float(iv);
  return (iv > 0 && iv < (1 << 20)) ? (float)iv : fv;
}

// ---------------- pass 4: decode boxes/landms/conf for the <=5000 survivors ----
__global__ __launch_bounds__(TPB)
void decode_kernel(const float* __restrict__ loc, const float* __restrict__ conf,
                   const float* __restrict__ landms, const float* __restrict__ priors,
                   const int* __restrict__ psx, const int* __restrict__ psy,
                   const int* __restrict__ sel, const int* __restrict__ meta, int P,
                   float4* __restrict__ boxes, float2* __restrict__ cs,
                   float* __restrict__ pts) {
  int rank = blockIdx.x * TPB + threadIdx.x;
  if (rank >= K_TOP) return;
  int M = meta[0];
  if (rank >= M) {
    boxes[rank] = make_float4(0.f, 0.f, 0.f, 0.f);
    cs[rank] = make_float2(0.f, 0.f);
    #pragma unroll
    for (int k = 0; k < 10; ++k) pts[rank*10 + k] = 0.f;
    return;
  }
  int n = sel[rank];
  int pi = n % P;
  float sx = scalar_to_float(psx), sy = scalar_to_float(psy);
  float4 pr = ((const float4*)priors)[pi];
  float4 lo = ((const float4*)loc)[n];
  // ctr = p[:2] + (loc[:2]*VAR0)*p[2:]
  float cx = __fadd_rn(pr.x, __fmul_rn(__fmul_rn(lo.x, 0.1f), pr.z));
  float cy = __fadd_rn(pr.y, __fmul_rn(__fmul_rn(lo.y, 0.1f), pr.w));
  // wh = p[2:] * exp(loc[2:]*VAR1)
  float w  = __fmul_rn(pr.z, expf(__fmul_rn(lo.z, 0.2f)));
  float h  = __fmul_rn(pr.w, expf(__fmul_rn(lo.w, 0.2f)));
  float hw = __fmul_rn(w, 0.5f), hh = __fmul_rn(h, 0.5f);
  float4 b;
  b.x = __fmul_rn(__fsub_rn(cx, hw), sx);
  b.y = __fmul_rn(__fsub_rn(cy, hh), sy);
  b.z = __fmul_rn(__fadd_rn(cx, hw), sx);
  b.w = __fmul_rn(__fadd_rn(cy, hh), sy);
  boxes[rank] = b;
  cs[rank] = ((const float2*)conf)[n];
  const float2* l2 = (const float2*)landms;
  #pragma unroll
  for (int k = 0; k < 5; ++k) {
    float2 lm = l2[(long long)n*5 + k];
    // pts = (p[:2] + ((p[2:]*l)*VAR0)) * scale
    float px = __fmul_rn(__fadd_rn(pr.x, __fmul_rn(__fmul_rn(pr.z, lm.x), 0.1f)), sx);
    float py = __fmul_rn(__fadd_rn(pr.y, __fmul_rn(__fmul_rn(pr.w, lm.y), 0.1f)), sy);
    pts[rank*10 + 2*k]     = px;
    pts[rank*10 + 2*k + 1] = py;
  }
}

// ---------------- pass 5: suppression bit-matrix ----------------
__device__ __forceinline__ float box_area(float4 a) {
  return __fmul_rn(fmaxf(__fsub_rn(a.z, a.x), 0.f), fmaxf(__fsub_rn(a.w, a.y), 0.f));
}

__global__ __launch_bounds__(64)
void iou_kernel(const float4* __restrict__ boxes, u64* __restrict__ mat) {
  int cb = blockIdx.x;            // col word 0..79
  int rb = blockIdx.y;            // row block 0..78
  int t  = threadIdx.x;
  __shared__ float4 cbox[64];
  __shared__ float  carea[64];
  int j0 = cb * 64;
  int jj = j0 + t;
  float4 bj = (jj < K_TOP) ? boxes[jj] : make_float4(0.f, 0.f, 0.f, 0.f);
  cbox[t]  = bj;
  carea[t] = box_area(bj);
  __syncthreads();
  int i = rb * 64 + t;
  if (i >= K_TOP) return;
  size_t widx = (size_t)i * W_WORDS + cb;
  if (j0 + 63 <= i) { mat[widx] = 0ull; return; }   // whole word is j<=i
  float4 bi = boxes[i];
  float ai = box_area(bi);
  u64 bits = 0;
  #pragma unroll 8
  for (int q = 0; q < 64; ++q) {
    float4 b = cbox[q];
    float iw = fmaxf(__fsub_rn(fminf(bi.z, b.z), fmaxf(bi.x, b.x)), 0.f);
    float ih = fmaxf(__fsub_rn(fminf(bi.w, b.w), fmaxf(bi.y, b.y)), 0.f);
    float inter = __fmul_rn(iw, ih);
    float uni = __fsub_rn(__fadd_rn(ai, carea[q]), inter);
    float iou = __fdiv_rn(inter, fmaxf(uni, 1e-12f));
    int j = j0 + q;
    bits |= (u64)((iou > NMS_THR_F) & (j > i)) << q;
  }
  mat[widx] = bits;
}

// ---------------- pass 6: greedy reduce, 4-wave redundant-state ---------------
// 256 threads = 4 waves. DMA copies split 3+3+2+2 per tile (per-wave counted
// vmcnt); raw s_barrier (NOT __syncthreads -> would drain vmcnt(0) and kill the
// pipeline). Each wave redundantly holds the full 80-word removed-state and
// computes the identical keep16 (integer ops, deterministic) -> no cross-wave
// communication. Resolve reads only the 16 diagonal words (1 ds_read_b64);
// full 80-word rows are read only for kept rows (keep-gated).
#define TR 16
#define PIPE 6
#define TILE_WORDS (TR * W_WORDS)            // 1280 u64
#define TILE_BYTES (TILE_WORDS * 8)          // 10240 B
#define NMS_TPB 256

__device__ __forceinline__ u64 readlane_u64(u64 v, int lane) {
  unsigned lo = (unsigned)__builtin_amdgcn_readlane((int)(unsigned)(v & 0xffffffffull), lane);
  unsigned hi = (unsigned)__builtin_amdgcn_readlane((int)(unsigned)(v >> 32), lane);
  return ((u64)hi << 32) | lo;
}

__device__ __forceinline__ void async_copy16(const void* g, void* l) {
  __builtin_amdgcn_global_load_lds((const __attribute__((address_space(1))) void*)g,
                                   (__attribute__((address_space(3))) void*)l,
                                   16, 0, 0);
}

// wave wv issues its share of tile's 10 KB: waves {0,1}: copies {0-2},{3-5};
// waves {2,3}: copies {6-7},{8-9}
__device__ __forceinline__ void issue_tile_w(const char* matb, u64* slotp, int tile,
                                             int lane, int wv) {
  const char* src = matb + (size_t)tile * TILE_BYTES + (size_t)lane * 16;
  char* dst = (char*)slotp;                  // wave-uniform; HW adds lane*16
  if (wv == 0) {
    async_copy16(src + 0*1024, dst + 0*1024);
    async_copy16(src + 1*1024, dst + 1*1024);
    async_copy16(src + 2*1024, dst + 2*1024);
  } else if (wv == 1) {
    async_copy16(src + 3*1024, dst + 3*1024);
    async_copy16(src + 4*1024, dst + 4*1024);
    async_copy16(src + 5*1024, dst + 5*1024);
  } else if (wv == 2) {
    async_copy16(src + 6*1024, dst + 6*1024);
    async_copy16(src + 7*1024, dst + 7*1024);
  } else {
    async_copy16(src + 8*1024, dst + 8*1024);
    async_copy16(src + 9*1024, dst + 9*1024);
  }
}

#define WAITV(n) asm volatile("s_waitcnt vmcnt(" #n ")" ::: "memory")

__global__ __launch_bounds__(NMS_TPB)
void nms_reduce_kernel(const u64* __restrict__ mat, const int* __restrict__ meta,
                       u64* __restrict__ keepw) {
  __shared__ __align__(16) u64 sbuf[PIPE][TILE_WORDS];   // 60 KB
  int lane = threadIdx.x & 63;
  int wv   = threadIdx.x >> 6;
  int M = meta[0];
  // drain the meta load so it can't pollute counted vmcnt arithmetic below
  asm volatile("s_waitcnt vmcnt(0) lgkmcnt(0)" ::: "memory");
  __builtin_amdgcn_sched_barrier(0);

  const char* matb = (const char*)mat;
  const int NT = (K_TOP + TR - 1) / TR;      // 313
  // deep prefetch: tiles 0..4 (each wave its own copies)
  issue_tile_w(matb, sbuf[0], 0, lane, wv);
  issue_tile_w(matb, sbuf[1], 1, lane, wv);
  issue_tile_w(matb, sbuf[2], 2, lane, wv);
  issue_tile_w(matb, sbuf[3], 3, lane, wv);
  issue_tile_w(matb, sbuf[4], 4, lane, wv);

  auto initw = [&](int w) -> u64 {
    int start = w * 64;
    if (M <= start) return ~0ull;            // fully invalid -> removed
    if (M >= start + 64) return 0ull;        // fully valid
    return (~0ull) << (M - start);           // bits >= M removed
  };
  u64 r0w = initw(lane);                       // removed-state word `lane`
  u64 r1w = (lane < 16) ? initw(64 + lane) : ~0ull; // lanes 0..15: words 64..79

  int slot_i = 0;                            // g % PIPE
  int slot_p = 5;                            // (g+5) % PIPE
  for (int g = 0; g < NT; ++g) {
    if (g + 5 < NT) {
      issue_tile_w(matb, sbuf[slot_p], g + 5, lane, wv);
      if (wv < 2) { WAITV(15); } else { WAITV(10); }   // tile g's own copies done
    } else {
      int rem = NT - 1 - g;
      if (wv < 2) {
        switch (rem) {
          case 4: WAITV(12); break;
          case 3: WAITV(9);  break;
          case 2: WAITV(6);  break;
          case 1: WAITV(3);  break;
          default: WAITV(0); break;
        }
      } else {
        switch (rem) {
          case 4: WAITV(8);  break;
          case 3: WAITV(6);  break;
          case 2: WAITV(4);  break;
          case 1: WAITV(2);  break;
          default: WAITV(0); break;
        }
      }
    }
    __builtin_amdgcn_sched_barrier(0);
    __builtin_amdgcn_s_barrier();            // BARRIER-A: tile g fully in LDS
    __builtin_amdgcn_sched_barrier(0);

    const u64* slot = sbuf[slot_i];
    // ---- resolve from the 16 diagonal words (1 ds_read_b64 per thread) ----
    int i0 = g * TR;
    int wi = i0 >> 6;                        // uniform 0..78 (16 | 64)
    int sh = i0 & 63;                        // 0,16,32,48
    u64 dvec = slot[(lane & 15) * W_WORDS + wi];   // lane r: diag word of row r
    u64 cur = (wi < 64) ? readlane_u64(r0w, wi) : readlane_u64(r1w, wi - 64);
    u64 d[TR];
    #pragma unroll
    for (int r = 0; r < TR; ++r) d[r] = readlane_u64(dvec, r);
    unsigned keep16 = 0;
    #pragma unroll
    for (int r = 0; r < TR; ++r) {           // branchless SALU keep-chain
      u64 removed = (cur >> (sh + r)) & 1ull;
      u64 live = (i0 + r < K_TOP) ? (removed ^ 1ull) : 0ull;
      cur |= d[r] & (0ull - live);           // in-tile forward suppression
      keep16 |= (unsigned)live << r;
    }
    // ---- keep-gated apply: read full rows only when kept (usually none) ----
    if (keep16) {
      #pragma unroll
      for (int r = 0; r < TR; ++r) {
        if ((keep16 >> r) & 1u) {
          r0w |= slot[r * W_WORDS + lane];
          r1w |= slot[r * W_WORDS + 64 + (lane & 15)];
        }
      }
    }
    __builtin_amdgcn_sched_barrier(0);
    __builtin_amdgcn_s_barrier();            // BARRIER-B: done reading slot g%6
    __builtin_amdgcn_sched_barrier(0);
    slot_i = (slot_i + 1 == PIPE) ? 0 : slot_i + 1;
    slot_p = (slot_p + 1 == PIPE) ? 0 : slot_p + 1;
  }
  if (wv == 0) {
    keepw[lane] = ~r0w;
    if (lane < 16) keepw[64 + lane] = ~r1w;
  }
}

// ---------------- pass 7: final masked write ----------------
__global__ __launch_bounds__(TPB)
void finalize_kernel(const float4* __restrict__ boxes, const float2* __restrict__ cs,
                     const float* __restrict__ pts, const u64* __restrict__ keepw,
                     float* __restrict__ out) {
  int rank = blockIdx.x * TPB + threadIdx.x;
  if (rank >= K_TOP) return;
  float m = ((keepw[rank >> 6] >> (rank & 63)) & 1ull) ? 1.0f : 0.0f;
  const int PTS_OFF  = K_TOP * 2;    // 10000
  const int BOX_OFF  = K_TOP * 12;   // 60000
  const int KEEP_OFF = K_TOP * 16;   // 80000
  float2 c = cs[rank];
  out[rank*2 + 0] = c.x * m;
  out[rank*2 + 1] = c.y * m;
  #pragma unroll
  for (int k = 0; k < 10; ++k) out[PTS_OFF + rank*10 + k] = pts[rank*10 + k] * m;
  float4 b = boxes[rank];
  out[BOX_OFF + rank*4 + 0] = b.x * m;
  out[BOX_OFF + rank*4 + 1] = b.y * m;
  out[BOX_OFF + rank*4 + 2] = b.z * m;
  out[BOX_OFF + rank*4 + 3] = b.w * m;
  out[KEEP_OFF + rank] = m;
}

extern "C" void kernel_launch(void* const* d_in, const int* in_sizes, int n_in,
                              void* d_out, int out_size, void* d_ws, size_t ws_size,
                              hipStream_t stream) {
  const float* loc    = (const float*)d_in[0];
  const float* conf   = (const float*)d_in[1];
  const float* landms = (const float*)d_in[2];
  const float* priors = (const float*)d_in[3];
  const int*   psx    = (const int*)d_in[4];
  const int*   psy    = (const int*)d_in[5];
  int P = in_sizes[3] / 4;
  int N = in_sizes[1] / 2;
  int NB = (N + CHUNK - 1) / CHUNK;

  char* ws = (char*)d_ws;
  size_t off = 0;
  u64*    mat    = (u64*)(ws + off);    off += (size_t)ROWS_PAD * W_WORDS * 8; // 3.24 MB
  u64*    keepw  = (u64*)(ws + off);    off += (size_t)W_WORDS * 8;
  float4* boxes  = (float4*)(ws + off); off += (size_t)K_TOP * 16;
  float2* cs     = (float2*)(ws + off); off += (size_t)K_TOP * 8;
  float*  pts    = (float*)(ws + off);  off += (size_t)K_TOP * 40;
  int*    sel    = (int*)(ws + off);    off += (size_t)K_TOP * 4;
  int*    counts = (int*)(ws + off);    off += (size_t)NB * 4;
  int*    offs   = (int*)(ws + off);    off += (size_t)NB * 4;
  int*    meta   = (int*)(ws + off);    off += 64;

  count_kernel<<<NB, TPB, 0, stream>>>(conf, N, counts);
  scan_kernel<<<1, TPB, 0, stream>>>(counts, offs, meta, NB);
  emit_kernel<<<NB, TPB, 0, stream>>>(conf, N, offs, sel);
  int dgrid = (K_TOP + TPB - 1) / TPB;
  decode_kernel<<<dgrid, TPB, 0, stream>>>(loc, conf, landms, priors, psx, psy,
                                           sel, meta, P, boxes, cs, pts);
  dim3 ig(W_WORDS, (K_TOP + 63) / 64);   // 80 x 79
  iou_kernel<<<ig, 64, 0, stream>>>(boxes, mat);
  nms_reduce_kernel<<<1, NMS_TPB, 0, stream>>>(mat, meta, keepw);
  finalize_kernel<<<dgrid, TPB, 0, stream>>>(boxes, cs, pts, keepw, (float*)d_out);
}

// Round 8
// 429.290 us; speedup vs baseline: 1.0331x; 1.0331x over previous
//
#include <hip/hip_runtime.h>

typedef unsigned long long u64;

#define K_TOP 5000
#define NMS_THR_F 0.4f
#define CONF_THR_F 0.6f
#define W_WORDS 80          // ceil(5000/64)=79, padded to 80
#define ROWS_PAD 5056       // mat rows allocated
#define CHUNK 8192          // elements per block in select pass
#define TPB 256

// ---------------- pass 1: per-block count of score>thr ----------------
__global__ __launch_bounds__(TPB)
void count_kernel(const float* __restrict__ conf, int N, int* __restrict__ counts) {
  int tid = threadIdx.x;
  long long base = (long long)blockIdx.x * CHUNK + (long long)tid * 32;
  int cnt = 0;
  if (base + 32 <= N) {
    const float4* c4 = (const float4*)conf;
    long long f0 = base >> 1;            // float4 index (2 anchors per float4)
    #pragma unroll
    for (int k = 0; k < 16; ++k) {
      float4 v = c4[f0 + k];
      cnt += (v.y > CONF_THR_F);
      cnt += (v.w > CONF_THR_F);
    }
  } else {
    for (int k = 0; k < 32; ++k) {
      long long n = base + k;
      if (n < N) cnt += (conf[2*n+1] > CONF_THR_F);
    }
  }
  __shared__ int s[TPB];
  s[tid] = cnt; __syncthreads();
  for (int d = TPB/2; d > 0; d >>= 1) {
    if (tid < d) s[tid] += s[tid+d];
    __syncthreads();
  }
  if (tid == 0) counts[blockIdx.x] = s[0];
}

// ---------------- pass 2: exclusive scan of block counts ----------------
__global__ __launch_bounds__(TPB)
void scan_kernel(const int* __restrict__ counts, int* __restrict__ offsets,
                 int* __restrict__ meta, int NB) {
  __shared__ int s[TPB];
  __shared__ int carry;
  int tid = threadIdx.x;
  if (tid == 0) carry = 0;
  __syncthreads();
  for (int base = 0; base < NB; base += TPB) {
    int idx = base + tid;
    int c = (idx < NB) ? counts[idx] : 0;
    s[tid] = c; __syncthreads();
    for (int d = 1; d < TPB; d <<= 1) {
      int v = (tid >= d) ? s[tid - d] : 0;
      __syncthreads();
      s[tid] += v;
      __syncthreads();
    }
    int excl = s[tid] - c + carry;
    if (idx < NB) offsets[idx] = excl;
    __syncthreads();                       // all threads done reading carry
    if (tid == 0) carry += s[TPB-1];
    __syncthreads();
  }
  if (tid == 0) {
    int total = carry;
    meta[0] = total < K_TOP ? total : K_TOP;  // M = number of valid slots
    meta[1] = total;
  }
}

// ---------------- pass 3: stable compaction of first K indices ----------------
__global__ __launch_bounds__(TPB)
void emit_kernel(const float* __restrict__ conf, int N,
                 const int* __restrict__ offsets, int* __restrict__ sel) {
  int tid = threadIdx.x;
  int boff = offsets[blockIdx.x];          // uniform
  if (boff >= K_TOP) return;               // uniform exit, before any barrier
  long long base = (long long)blockIdx.x * CHUNK + (long long)tid * 32;
  unsigned mbits = 0;
  if (base + 32 <= N) {
    const float4* c4 = (const float4*)conf;
    long long f0 = base >> 1;
    #pragma unroll
    for (int k = 0; k < 16; ++k) {
      float4 v = c4[f0 + k];
      mbits |= (unsigned)(v.y > CONF_THR_F) << (2*k);
      mbits |= (unsigned)(v.w > CONF_THR_F) << (2*k+1);
    }
  } else {
    for (int k = 0; k < 32; ++k) {
      long long n = base + k;
      if (n < N && conf[2*n+1] > CONF_THR_F) mbits |= 1u << k;
    }
  }
  int cnt = __popc(mbits);
  __shared__ int s[TPB];
  s[tid] = cnt; __syncthreads();
  for (int d = 1; d < TPB; d <<= 1) {
    int v = (tid >= d) ? s[tid - d] : 0;
    __syncthreads();
    s[tid] += v;
    __syncthreads();
  }
  int rank = boff + s[tid] - cnt;          // exclusive prefix within block + block offset
  if (mbits && rank < K_TOP) {
    for (int k = 0; k < 32; ++k) {
      if ((mbits >> k) & 1u) {
        if (rank < K_TOP) sel[rank] = (int)(base + k);
        ++rank;
      }
    }
  }
}

// scalar inputs arrive as 1-element arrays; dtype could be int32 or float32.
// Decode both ways and pick the interpretation in a sane range (exact for 1664
// either way; 1664.0f's bit pattern reads as 1.15e9 which is rejected).
__device__ __forceinline__ float scalar_to_float(const int* p) {
  int iv = *p;
  float fv = __int_as_float(iv);
  return (iv > 0 && iv < (1 << 20)) ? (float)iv : fv;
}

// ---------------- pass 4: decode boxes/landms/conf for the <=5000 survivors ----
__global__ __launch_bounds__(TPB)
void decode_kernel(const float* __restrict__ loc, const float* __restrict__ conf,
                   const float* __restrict__ landms, const float* __restrict__ priors,
                   const int* __restrict__ psx, const int* __restrict__ psy,
                   const int* __restrict__ sel, const int* __restrict__ meta, int P,
                   float4* __restrict__ boxes, float2* __restrict__ cs,
                   float* __restrict__ pts) {
  int rank = blockIdx.x * TPB + threadIdx.x;
  if (rank >= K_TOP) return;
  int M = meta[0];
  if (rank >= M) {
    boxes[rank] = make_float4(0.f, 0.f, 0.f, 0.f);
    cs[rank] = make_float2(0.f, 0.f);
    #pragma unroll
    for (int k = 0; k < 10; ++k) pts[rank*10 + k] = 0.f;
    return;
  }
  int n = sel[rank];
  int pi = n % P;
  float sx = scalar_to_float(psx), sy = scalar_to_float(psy);
  float4 pr = ((const float4*)priors)[pi];
  float4 lo = ((const float4*)loc)[n];
  // ctr = p[:2] + (loc[:2]*VAR0)*p[2:]
  float cx = __fadd_rn(pr.x, __fmul_rn(__fmul_rn(lo.x, 0.1f), pr.z));
  float cy = __fadd_rn(pr.y, __fmul_rn(__fmul_rn(lo.y, 0.1f), pr.w));
  // wh = p[2:] * exp(loc[2:]*VAR1)
  float w  = __fmul_rn(pr.z, expf(__fmul_rn(lo.z, 0.2f)));
  float h  = __fmul_rn(pr.w, expf(__fmul_rn(lo.w, 0.2f)));
  float hw = __fmul_rn(w, 0.5f), hh = __fmul_rn(h, 0.5f);
  float4 b;
  b.x = __fmul_rn(__fsub_rn(cx, hw), sx);
  b.y = __fmul_rn(__fsub_rn(cy, hh), sy);
  b.z = __fmul_rn(__fadd_rn(cx, hw), sx);
  b.w = __fmul_rn(__fadd_rn(cy, hh), sy);
  boxes[rank] = b;
  cs[rank] = ((const float2*)conf)[n];
  const float2* l2 = (const float2*)landms;
  #pragma unroll
  for (int k = 0; k < 5; ++k) {
    float2 lm = l2[(long long)n*5 + k];
    // pts = (p[:2] + ((p[2:]*l)*VAR0)) * scale
    float px = __fmul_rn(__fadd_rn(pr.x, __fmul_rn(__fmul_rn(pr.z, lm.x), 0.1f)), sx);
    float py = __fmul_rn(__fadd_rn(pr.y, __fmul_rn(__fmul_rn(pr.w, lm.y), 0.1f)), sy);
    pts[rank*10 + 2*k]     = px;
    pts[rank*10 + 2*k + 1] = py;
  }
}

// ---------------- pass 5: suppression bit-matrix ----------------
__device__ __forceinline__ float box_area(float4 a) {
  return __fmul_rn(fmaxf(__fsub_rn(a.z, a.x), 0.f), fmaxf(__fsub_rn(a.w, a.y), 0.f));
}

__global__ __launch_bounds__(64)
void iou_kernel(const float4* __restrict__ boxes, u64* __restrict__ mat) {
  int cb = blockIdx.x;            // col word 0..79
  int rb = blockIdx.y;            // row block 0..78
  int t  = threadIdx.x;
  __shared__ float4 cbox[64];
  __shared__ float  carea[64];
  int j0 = cb * 64;
  int jj = j0 + t;
  float4 bj = (jj < K_TOP) ? boxes[jj] : make_float4(0.f, 0.f, 0.f, 0.f);
  cbox[t]  = bj;
  carea[t] = box_area(bj);
  __syncthreads();
  int i = rb * 64 + t;
  if (i >= K_TOP) return;
  size_t widx = (size_t)i * W_WORDS + cb;
  if (j0 + 63 <= i) { mat[widx] = 0ull; return; }   // whole word is j<=i
  float4 bi = boxes[i];
  float ai = box_area(bi);
  u64 bits = 0;
  #pragma unroll 8
  for (int q = 0; q < 64; ++q) {
    float4 b = cbox[q];
    float iw = fmaxf(__fsub_rn(fminf(bi.z, b.z), fmaxf(bi.x, b.x)), 0.f);
    float ih = fmaxf(__fsub_rn(fminf(bi.w, b.w), fmaxf(bi.y, b.y)), 0.f);
    float inter = __fmul_rn(iw, ih);
    float uni = __fsub_rn(__fadd_rn(ai, carea[q]), inter);
    float iou = __fdiv_rn(inter, fmaxf(uni, 1e-12f));
    int j = j0 + q;
    bits |= (u64)((iou > NMS_THR_F) & (j > i)) << q;
  }
  mat[widx] = bits;
}

// ---------------- pass 6: greedy reduce, fetch-on-keep (plain loads) ----------
// Single wave. State: 80 removed-words, word w on lane w (r0w) / lane w-64
// (r1w, lanes 0..15). Per 64-block: cur = readlane(state, b); alive = ~cur;
// iterate set bits via ctz. Each kept row fetches its full 640-B mask with two
// PLAIN loads (coalesced burst; compiler inserts the exact waitcnts) and ORs it
// into the state. The in-block suppression word D is lane b of the fetched
// mask -- no separate diag array needed. Dead rows cost nothing. All values
// steering control flow (alive, r) are wave-uniform -> no divergence.
__device__ __forceinline__ u64 readlane_u64(u64 v, int lane) {
  unsigned lo = (unsigned)__builtin_amdgcn_readlane((int)(unsigned)(v & 0xffffffffull), lane);
  unsigned hi = (unsigned)__builtin_amdgcn_readlane((int)(unsigned)(v >> 32), lane);
  return ((u64)hi << 32) | lo;
}

__global__ __launch_bounds__(64)
void nms_reduce_kernel(const u64* __restrict__ mat, const int* __restrict__ meta,
                       u64* __restrict__ keepw) {
  int lane = threadIdx.x;
  int M = meta[0];
  auto initw = [&](int w) -> u64 {
    int start = w * 64;
    if (M <= start) return ~0ull;        // fully invalid -> removed
    if (M >= start + 64) return 0ull;    // fully valid
    return (~0ull) << (M - start);       // bits >= M removed
  };
  u64 r0w = initw(lane);                 // removed-state word `lane`
  u64 r1w = (lane < 16) ? initw(64 + lane) : ~0ull;  // lanes 0..15: words 64..79

  const int NBLK = (K_TOP + 63) / 64;    // 79
  for (int b = 0; b < NBLK; ++b) {
    u64 cur = (b < 64) ? readlane_u64(r0w, b) : readlane_u64(r1w, b - 64);
    u64 alive = ~cur;                    // candidate rows (invalid tail pre-removed)
    while (alive) {
      int r = (int)__builtin_ctzll(alive);
      size_t base = (size_t)(b * 64 + r) * W_WORDS;   // row i = b*64+r is KEPT
      u64 m0 = mat[base + lane];                      // word `lane` of row i
      u64 m1 = mat[base + 64 + (lane & 15)];          // words 64..79
      u64 D = readlane_u64(m0, b);       // in-block forward suppression (j>i only)
      alive &= ~(D | (1ull << r));
      r0w |= m0;
      r1w |= m1;                         // lanes 16..63 garbage, never stored
    }
  }
  keepw[lane] = ~r0w;
  if (lane < 16) keepw[64 + lane] = ~r1w;
}

// ---------------- pass 7: final masked write ----------------
__global__ __launch_bounds__(TPB)
void finalize_kernel(const float4* __restrict__ boxes, const float2* __restrict__ cs,
                     const float* __restrict__ pts, const u64* __restrict__ keepw,
                     float* __restrict__ out) {
  int rank = blockIdx.x * TPB + threadIdx.x;
  if (rank >= K_TOP) return;
  float m = ((keepw[rank >> 6] >> (rank & 63)) & 1ull) ? 1.0f : 0.0f;
  const int PTS_OFF  = K_TOP * 2;    // 10000
  const int BOX_OFF  = K_TOP * 12;   // 60000
  const int KEEP_OFF = K_TOP * 16;   // 80000
  float2 c = cs[rank];
  out[rank*2 + 0] = c.x * m;
  out[rank*2 + 1] = c.y * m;
  #pragma unroll
  for (int k = 0; k < 10; ++k) out[PTS_OFF + rank*10 + k] = pts[rank*10 + k] * m;
  float4 b = boxes[rank];
  out[BOX_OFF + rank*4 + 0] = b.x * m;
  out[BOX_OFF + rank*4 + 1] = b.y * m;
  out[BOX_OFF + rank*4 + 2] = b.z * m;
  out[BOX_OFF + rank*4 + 3] = b.w * m;
  out[KEEP_OFF + rank] = m;
}

extern "C" void kernel_launch(void* const* d_in, const int* in_sizes, int n_in,
                              void* d_out, int out_size, void* d_ws, size_t ws_size,
                              hipStream_t stream) {
  const float* loc    = (const float*)d_in[0];
  const float* conf   = (const float*)d_in[1];
  const float* landms = (const float*)d_in[2];
  const float* priors = (const float*)d_in[3];
  const int*   psx    = (const int*)d_in[4];
  const int*   psy    = (const int*)d_in[5];
  int P = in_sizes[3] / 4;
  int N = in_sizes[1] / 2;
  int NB = (N + CHUNK - 1) / CHUNK;

  char* ws = (char*)d_ws;
  size_t off = 0;
  u64*    mat    = (u64*)(ws + off);    off += (size_t)ROWS_PAD * W_WORDS * 8; // 3.24 MB
  u64*    keepw  = (u64*)(ws + off);    off += (size_t)W_WORDS * 8;
  float4* boxes  = (float4*)(ws + off); off += (size_t)K_TOP * 16;
  float2* cs     = (float2*)(ws + off); off += (size_t)K_TOP * 8;
  float*  pts    = (float*)(ws + off);  off += (size_t)K_TOP * 40;
  int*    sel    = (int*)(ws + off);    off += (size_t)K_TOP * 4;
  int*    counts = (int*)(ws + off);    off += (size_t)NB * 4;
  int*    offs   = (int*)(ws + off);    off += (size_t)NB * 4;
  int*    meta   = (int*)(ws + off);    off += 64;

  count_kernel<<<NB, TPB, 0, stream>>>(conf, N, counts);
  scan_kernel<<<1, TPB, 0, stream>>>(counts, offs, meta, NB);
  emit_kernel<<<NB, TPB, 0, stream>>>(conf, N, offs, sel);
  int dgrid = (K_TOP + TPB - 1) / TPB;
  decode_kernel<<<dgrid, TPB, 0, stream>>>(loc, conf, landms, priors, psx, psy,
                                           sel, meta, P, boxes, cs, pts);
  dim3 ig(W_WORDS, (K_TOP + 63) / 64);   // 80 x 79
  iou_kernel<<<ig, 64, 0, stream>>>(boxes, mat);
  nms_reduce_kernel<<<1, 64, 0, stream>>>(mat, meta, keepw);
  finalize_kernel<<<dgrid, TPB, 0, stream>>>(boxes, cs, pts, keepw, (float*)d_out);
}

// Round 9
// 309.778 us; speedup vs baseline: 1.4316x; 1.3858x over previous
//
#include <hip/hip_runtime.h>

typedef unsigned long long u64;

#define K_TOP 5000
#define NMS_THR_F 0.4f
#define CONF_THR_F 0.6f
#define W_WORDS 80          // ceil(5000/64)=79, padded to 80
#define ROWS_PAD 5056       // mat rows allocated
#define DIAG_N 5120         // diag entries (79*64=5056, padded)
#define CHUNK 8192          // elements per block in select pass
#define TPB 256

// ---------------- pass 1: per-block count of score>thr ----------------
__global__ __launch_bounds__(TPB)
void count_kernel(const float* __restrict__ conf, int N, int* __restrict__ counts) {
  int tid = threadIdx.x;
  long long base = (long long)blockIdx.x * CHUNK + (long long)tid * 32;
  int cnt = 0;
  if (base + 32 <= N) {
    const float4* c4 = (const float4*)conf;
    long long f0 = base >> 1;            // float4 index (2 anchors per float4)
    #pragma unroll
    for (int k = 0; k < 16; ++k) {
      float4 v = c4[f0 + k];
      cnt += (v.y > CONF_THR_F);
      cnt += (v.w > CONF_THR_F);
    }
  } else {
    for (int k = 0; k < 32; ++k) {
      long long n = base + k;
      if (n < N) cnt += (conf[2*n+1] > CONF_THR_F);
    }
  }
  __shared__ int s[TPB];
  s[tid] = cnt; __syncthreads();
  for (int d = TPB/2; d > 0; d >>= 1) {
    if (tid < d) s[tid] += s[tid+d];
    __syncthreads();
  }
  if (tid == 0) counts[blockIdx.x] = s[0];
}

// ---------------- pass 2: exclusive scan of block counts ----------------
__global__ __launch_bounds__(TPB)
void scan_kernel(const int* __restrict__ counts, int* __restrict__ offsets,
                 int* __restrict__ meta, int NB) {
  __shared__ int s[TPB];
  __shared__ int carry;
  int tid = threadIdx.x;
  if (tid == 0) carry = 0;
  __syncthreads();
  for (int base = 0; base < NB; base += TPB) {
    int idx = base + tid;
    int c = (idx < NB) ? counts[idx] : 0;
    s[tid] = c; __syncthreads();
    for (int d = 1; d < TPB; d <<= 1) {
      int v = (tid >= d) ? s[tid - d] : 0;
      __syncthreads();
      s[tid] += v;
      __syncthreads();
    }
    int excl = s[tid] - c + carry;
    if (idx < NB) offsets[idx] = excl;
    __syncthreads();                       // all threads done reading carry
    if (tid == 0) carry += s[TPB-1];
    __syncthreads();
  }
  if (tid == 0) {
    int total = carry;
    meta[0] = total < K_TOP ? total : K_TOP;  // M = number of valid slots
    meta[1] = total;
  }
}

// ---------------- pass 3: stable compaction of first K indices ----------------
__global__ __launch_bounds__(TPB)
void emit_kernel(const float* __restrict__ conf, int N,
                 const int* __restrict__ offsets, int* __restrict__ sel) {
  int tid = threadIdx.x;
  int boff = offsets[blockIdx.x];          // uniform
  if (boff >= K_TOP) return;               // uniform exit, before any barrier
  long long base = (long long)blockIdx.x * CHUNK + (long long)tid * 32;
  unsigned mbits = 0;
  if (base + 32 <= N) {
    const float4* c4 = (const float4*)conf;
    long long f0 = base >> 1;
    #pragma unroll
    for (int k = 0; k < 16; ++k) {
      float4 v = c4[f0 + k];
      mbits |= (unsigned)(v.y > CONF_THR_F) << (2*k);
      mbits |= (unsigned)(v.w > CONF_THR_F) << (2*k+1);
    }
  } else {
    for (int k = 0; k < 32; ++k) {
      long long n = base + k;
      if (n < N && conf[2*n+1] > CONF_THR_F) mbits |= 1u << k;
    }
  }
  int cnt = __popc(mbits);
  __shared__ int s[TPB];
  s[tid] = cnt; __syncthreads();
  for (int d = 1; d < TPB; d <<= 1) {
    int v = (tid >= d) ? s[tid - d] : 0;
    __syncthreads();
    s[tid] += v;
    __syncthreads();
  }
  int rank = boff + s[tid] - cnt;          // exclusive prefix within block + block offset
  if (mbits && rank < K_TOP) {
    for (int k = 0; k < 32; ++k) {
      if ((mbits >> k) & 1u) {
        if (rank < K_TOP) sel[rank] = (int)(base + k);
        ++rank;
      }
    }
  }
}

// scalar inputs arrive as 1-element arrays; dtype could be int32 or float32.
// Decode both ways and pick the interpretation in a sane range (exact for 1664
// either way; 1664.0f's bit pattern reads as 1.15e9 which is rejected).
__device__ __forceinline__ float scalar_to_float(const int* p) {
  int iv = *p;
  float fv = __int_as_float(iv);
  return (iv > 0 && iv < (1 << 20)) ? (float)iv : fv;
}

// ---------------- pass 4: decode boxes/landms/conf for the <=5000 survivors ----
__global__ __launch_bounds__(TPB)
void decode_kernel(const float* __restrict__ loc, const float* __restrict__ conf,
                   const float* __restrict__ landms, const float* __restrict__ priors,
                   const int* __restrict__ psx, const int* __restrict__ psy,
                   const int* __restrict__ sel, const int* __restrict__ meta, int P,
                   float4* __restrict__ boxes, float2* __restrict__ cs,
                   float* __restrict__ pts) {
  int rank = blockIdx.x * TPB + threadIdx.x;
  if (rank >= K_TOP) return;
  int M = meta[0];
  if (rank >= M) {
    boxes[rank] = make_float4(0.f, 0.f, 0.f, 0.f);
    cs[rank] = make_float2(0.f, 0.f);
    #pragma unroll
    for (int k = 0; k < 10; ++k) pts[rank*10 + k] = 0.f;
    return;
  }
  int n = sel[rank];
  int pi = n % P;
  float sx = scalar_to_float(psx), sy = scalar_to_float(psy);
  float4 pr = ((const float4*)priors)[pi];
  float4 lo = ((const float4*)loc)[n];
  // ctr = p[:2] + (loc[:2]*VAR0)*p[2:]
  float cx = __fadd_rn(pr.x, __fmul_rn(__fmul_rn(lo.x, 0.1f), pr.z));
  float cy = __fadd_rn(pr.y, __fmul_rn(__fmul_rn(lo.y, 0.1f), pr.w));
  // wh = p[2:] * exp(loc[2:]*VAR1)
  float w  = __fmul_rn(pr.z, expf(__fmul_rn(lo.z, 0.2f)));
  float h  = __fmul_rn(pr.w, expf(__fmul_rn(lo.w, 0.2f)));
  float hw = __fmul_rn(w, 0.5f), hh = __fmul_rn(h, 0.5f);
  float4 b;
  b.x = __fmul_rn(__fsub_rn(cx, hw), sx);
  b.y = __fmul_rn(__fsub_rn(cy, hh), sy);
  b.z = __fmul_rn(__fadd_rn(cx, hw), sx);
  b.w = __fmul_rn(__fadd_rn(cy, hh), sy);
  boxes[rank] = b;
  cs[rank] = ((const float2*)conf)[n];
  const float2* l2 = (const float2*)landms;
  #pragma unroll
  for (int k = 0; k < 5; ++k) {
    float2 lm = l2[(long long)n*5 + k];
    // pts = (p[:2] + ((p[2:]*l)*VAR0)) * scale
    float px = __fmul_rn(__fadd_rn(pr.x, __fmul_rn(__fmul_rn(pr.z, lm.x), 0.1f)), sx);
    float py = __fmul_rn(__fadd_rn(pr.y, __fmul_rn(__fmul_rn(pr.w, lm.y), 0.1f)), sy);
    pts[rank*10 + 2*k]     = px;
    pts[rank*10 + 2*k + 1] = py;
  }
}

// ---------------- pass 5: suppression bit-matrix + diag array (r6-proven) -----
__device__ __forceinline__ float box_area(float4 a) {
  return __fmul_rn(fmaxf(__fsub_rn(a.z, a.x), 0.f), fmaxf(__fsub_rn(a.w, a.y), 0.f));
}

__global__ __launch_bounds__(64)
void iou_kernel(const float4* __restrict__ boxes, u64* __restrict__ mat,
                u64* __restrict__ diag) {
  int cb = blockIdx.x;            // col word 0..79
  int rb = blockIdx.y;            // row block 0..78
  int t  = threadIdx.x;
  __shared__ float4 cbox[64];
  __shared__ float  carea[64];
  int j0 = cb * 64;
  int jj = j0 + t;
  float4 bj = (jj < K_TOP) ? boxes[jj] : make_float4(0.f, 0.f, 0.f, 0.f);
  cbox[t]  = bj;
  carea[t] = box_area(bj);
  __syncthreads();
  int i = rb * 64 + t;
  if (i >= K_TOP) return;
  size_t widx = (size_t)i * W_WORDS + cb;
  if (j0 + 63 <= i) {                    // whole word is j<=i
    mat[widx] = 0ull;
    if (cb == rb) diag[i] = 0ull;        // last diag-block row still writes diag
    return;
  }
  float4 bi = boxes[i];
  float ai = box_area(bi);
  u64 bits = 0;
  #pragma unroll 8
  for (int q = 0; q < 64; ++q) {
    float4 b = cbox[q];
    float iw = fmaxf(__fsub_rn(fminf(bi.z, b.z), fmaxf(bi.x, b.x)), 0.f);
    float ih = fmaxf(__fsub_rn(fminf(bi.w, b.w), fmaxf(bi.y, b.y)), 0.f);
    float inter = __fmul_rn(iw, ih);
    float uni = __fsub_rn(__fadd_rn(ai, carea[q]), inter);
    float iou = __fdiv_rn(inter, fmaxf(uni, 1e-12f));
    int j = j0 + q;
    bits |= (u64)((iou > NMS_THR_F) & (j > i)) << q;
  }
  mat[widx] = bits;
  if (cb == rb) diag[i] = bits;          // in-block suppression word (j>i only)
}

// ---------------- pass 6: greedy reduce, diag-resolve + per-block row fetch ---
// Single wave. Two-level structure that keeps memory OFF the keep-chain:
//  (a) in-block resolve uses only the 64x64 diag block (one coalesced 512-B
//      load per block, prefetched 2 blocks ahead into registers): the
//      keep-chain is pure SALU/VALU (ctz + readlane + and), ~40 cy/keep.
//  (b) kept rows' full 640-B masks are fetched AFTER resolve, in parallel
//      groups of 4 (plain loads into named slots -> compiler issues all 8
//      loads then one waitcnt): one memory latency per block-with-keeps,
//      not per keep.
__device__ __forceinline__ u64 readlane_u64(u64 v, int lane) {
  unsigned lo = (unsigned)__builtin_amdgcn_readlane((int)(unsigned)(v & 0xffffffffull), lane);
  unsigned hi = (unsigned)__builtin_amdgcn_readlane((int)(unsigned)(v >> 32), lane);
  return ((u64)hi << 32) | lo;
}

__global__ __launch_bounds__(64)
void nms_reduce_kernel(const u64* __restrict__ mat, const u64* __restrict__ diag,
                       const int* __restrict__ meta, u64* __restrict__ keepw) {
  int lane = threadIdx.x;
  int M = meta[0];
  auto initw = [&](int w) -> u64 {
    int start = w * 64;
    if (M <= start) return ~0ull;        // fully invalid -> removed
    if (M >= start + 64) return 0ull;    // fully valid
    return (~0ull) << (M - start);       // bits >= M removed
  };
  u64 r0w = initw(lane);                 // removed-state word `lane`
  u64 r1w = (lane < 16) ? initw(64 + lane) : ~0ull;  // lanes 0..15: words 64..79

  const int NBLK = (K_TOP + 63) / 64;    // 79
  u64 dvA = diag[lane];                  // diag of block 0
  u64 dvB = diag[64 + lane];             // diag of block 1 (NBLK >= 2)
  for (int b = 0; b < NBLK; ++b) {
    u64 dvC = (b + 2 < NBLK) ? diag[(size_t)(b + 2) * 64 + lane] : 0ull;
    u64 cur = (b < 64) ? readlane_u64(r0w, b) : readlane_u64(r1w, b - 64);
    u64 alive = ~cur;                    // candidates (invalid tail pre-removed)
    // ---- pure-ALU resolve: every pick is a keep ----
    u64 keeps = 0ull;
    while (alive) {
      int r = (int)__builtin_ctzll(alive);
      keeps |= (1ull << r);
      alive &= ~(readlane_u64(dvA, r) | (1ull << r));
    }
    // ---- parallel fetch + apply of kept rows, 4 at a time ----
    while (keeps) {
      int k0 = (int)__builtin_ctzll(keeps); keeps &= keeps - 1;
      int k1 = -1, k2 = -1, k3 = -1;
      if (keeps) { k1 = (int)__builtin_ctzll(keeps); keeps &= keeps - 1; }
      if (k1 >= 0 && keeps) { k2 = (int)__builtin_ctzll(keeps); keeps &= keeps - 1; }
      if (k2 >= 0 && keeps) { k3 = (int)__builtin_ctzll(keeps); keeps &= keeps - 1; }
      size_t base0 = (size_t)(b * 64 + k0) * W_WORDS;
      u64 a0 = mat[base0 + lane];
      u64 a1 = mat[base0 + 64 + (lane & 15)];
      u64 b0 = 0, b1 = 0, c0 = 0, c1 = 0, d0 = 0, d1 = 0;
      if (k1 >= 0) {
        size_t bb = (size_t)(b * 64 + k1) * W_WORDS;
        b0 = mat[bb + lane]; b1 = mat[bb + 64 + (lane & 15)];
      }
      if (k2 >= 0) {
        size_t bb = (size_t)(b * 64 + k2) * W_WORDS;
        c0 = mat[bb + lane]; c1 = mat[bb + 64 + (lane & 15)];
      }
      if (k3 >= 0) {
        size_t bb = (size_t)(b * 64 + k3) * W_WORDS;
        d0 = mat[bb + lane]; d1 = mat[bb + 64 + (lane & 15)];
      }
      r0w |= (a0 | b0) | (c0 | d0);
      r1w |= (a1 | b1) | (c1 | d1);      // lanes 16..63 garbage, never stored
    }
    dvA = dvB; dvB = dvC;
  }
  keepw[lane] = ~r0w;
  if (lane < 16) keepw[64 + lane] = ~r1w;
}

// ---------------- pass 7: final masked write ----------------
__global__ __launch_bounds__(TPB)
void finalize_kernel(const float4* __restrict__ boxes, const float2* __restrict__ cs,
                     const float* __restrict__ pts, const u64* __restrict__ keepw,
                     float* __restrict__ out) {
  int rank = blockIdx.x * TPB + threadIdx.x;
  if (rank >= K_TOP) return;
  float m = ((keepw[rank >> 6] >> (rank & 63)) & 1ull) ? 1.0f : 0.0f;
  const int PTS_OFF  = K_TOP * 2;    // 10000
  const int BOX_OFF  = K_TOP * 12;   // 60000
  const int KEEP_OFF = K_TOP * 16;   // 80000
  float2 c = cs[rank];
  out[rank*2 + 0] = c.x * m;
  out[rank*2 + 1] = c.y * m;
  #pragma unroll
  for (int k = 0; k < 10; ++k) out[PTS_OFF + rank*10 + k] = pts[rank*10 + k] * m;
  float4 b = boxes[rank];
  out[BOX_OFF + rank*4 + 0] = b.x * m;
  out[BOX_OFF + rank*4 + 1] = b.y * m;
  out[BOX_OFF + rank*4 + 2] = b.z * m;
  out[BOX_OFF + rank*4 + 3] = b.w * m;
  out[KEEP_OFF + rank] = m;
}

extern "C" void kernel_launch(void* const* d_in, const int* in_sizes, int n_in,
                              void* d_out, int out_size, void* d_ws, size_t ws_size,
                              hipStream_t stream) {
  const float* loc    = (const float*)d_in[0];
  const float* conf   = (const float*)d_in[1];
  const float* landms = (const float*)d_in[2];
  const float* priors = (const float*)d_in[3];
  const int*   psx    = (const int*)d_in[4];
  const int*   psy    = (const int*)d_in[5];
  int P = in_sizes[3] / 4;
  int N = in_sizes[1] / 2;
  int NB = (N + CHUNK - 1) / CHUNK;

  char* ws = (char*)d_ws;
  size_t off = 0;
  u64*    mat    = (u64*)(ws + off);    off += (size_t)ROWS_PAD * W_WORDS * 8; // 3.24 MB
  u64*    diag   = (u64*)(ws + off);    off += (size_t)DIAG_N * 8;             // 40 KB
  u64*    keepw  = (u64*)(ws + off);    off += (size_t)W_WORDS * 8;
  float4* boxes  = (float4*)(ws + off); off += (size_t)K_TOP * 16;
  float2* cs     = (float2*)(ws + off); off += (size_t)K_TOP * 8;
  float*  pts    = (float*)(ws + off);  off += (size_t)K_TOP * 40;
  int*    sel    = (int*)(ws + off);    off += (size_t)K_TOP * 4;
  int*    counts = (int*)(ws + off);    off += (size_t)NB * 4;
  int*    offs   = (int*)(ws + off);    off += (size_t)NB * 4;
  int*    meta   = (int*)(ws + off);    off += 64;

  count_kernel<<<NB, TPB, 0, stream>>>(conf, N, counts);
  scan_kernel<<<1, TPB, 0, stream>>>(counts, offs, meta, NB);
  emit_kernel<<<NB, TPB, 0, stream>>>(conf, N, offs, sel);
  int dgrid = (K_TOP + TPB - 1) / TPB;
  decode_kernel<<<dgrid, TPB, 0, stream>>>(loc, conf, landms, priors, psx, psy,
                                           sel, meta, P, boxes, cs, pts);
  dim3 ig(W_WORDS, (K_TOP + 63) / 64);   // 80 x 79
  iou_kernel<<<ig, 64, 0, stream>>>(boxes, mat, diag);
  nms_reduce_kernel<<<1, 64, 0, stream>>>(mat, diag, meta, keepw);
  finalize_kernel<<<dgrid, TPB, 0, stream>>>(boxes, cs, pts, keepw, (float*)d_out);
}